// Round 5
// baseline (359.167 us; speedup 1.0000x reference)
//
#include <hip/hip_runtime.h>
#include <hip/hip_bf16.h>

// LengthRegulator (FastSpeech): expanded gather + mel_len + mel_mask.
// Outputs concatenated flat in d_out as float32:
//   [0, B*max_len*D)                      expanded
//   [B*max_len*D, +B)                     mel_len (as float)
//   [B*max_len*D + B, +B*max_len)         mel_mask (0.0 / 1.0)
//
// R4 -> R5: drop non-temporal stores (bypassing L2 defeats write-combining;
// harness fill hits 6.4 TB/s with normal stores). 256-thread blocks handle
// 2 tokens each (wave-uniform split), tail blocks cover 8 frames.

#define S_TOK 1024  // tokens per sequence
#define B_SZ  32    // batch
#define NSB   (S_TOK / 2)  // scatter blocks per batch (2 tokens/block)

// One wave per batch: 16 durations/lane serial prefix + wave shuffle scan.
__global__ __launch_bounds__(64)
void lr_scan_kernel(const int* __restrict__ dur,
                    int* __restrict__ csum,
                    float* __restrict__ mel_len_out) {
    const int b = blockIdx.x;
    const int lane = threadIdx.x;
    const int* __restrict__ d = dur + b * S_TOK;

    int v[16];
    int sum = 0;
#pragma unroll
    for (int k = 0; k < 16; ++k) {
        v[k] = d[lane * 16 + k];
        sum += v[k];
    }
    int run = 0;
#pragma unroll
    for (int k = 0; k < 16; ++k) { run += v[k]; v[k] = run; }

    int tot = sum;
#pragma unroll
    for (int off = 1; off < 64; off <<= 1) {
        int n = __shfl_up(tot, off, 64);
        if (lane >= off) tot += n;
    }
    const int excl = tot - sum;

#pragma unroll
    for (int k = 0; k < 16; ++k)
        csum[b * S_TOK + lane * 16 + k] = v[k] + excl;
    if (lane == 63) mel_len_out[b] = (float)tot;
}

// Fused scatter + tail-zero + mask. 256 threads.
// blockIdx.x in [0, NSB): tokens s = 2*bx + (tid>>7); each 128-thread half
//   copies x[b,s,:] to frames [c[s-1], c[s]) and writes mask=0.
// blockIdx.x in [NSB, NSB+tail): zero-fill 8 frames from mel + 8*(bx-NSB),
//   4 frames per half; mask=1.
__global__ __launch_bounds__(256)
void lr_fused_kernel(const float* __restrict__ x,
                     const int* __restrict__ csum,
                     float* __restrict__ out,
                     float* __restrict__ mask,
                     int D, int max_len) {
    const int b = blockIdx.y;
    const int tid = threadIdx.x;
    const int half = tid >> 7;       // wave-uniform (waves 0-1 vs 2-3)
    const int lt = tid & 127;
    const int* __restrict__ c = csum + b * S_TOK;
    const int d4 = D >> 2;

    if (blockIdx.x < NSB) {
        const int s = blockIdx.x * 2 + half;
        const int base = (s == 0) ? 0 : c[s - 1];
        const int dur = c[s] - base;

        const float4 v =
            ((const float4*)(x + ((size_t)b * S_TOK + s) * (size_t)D))[lt];
        float4* __restrict__ o =
            (float4*)(out + ((size_t)b * max_len + base) * (size_t)D) + lt;
        for (int r = 0; r < dur; ++r)
            o[(size_t)r * d4] = v;
        if (lt < dur)
            mask[(size_t)b * max_len + base + lt] = 0.0f;
    } else {
        const int mel = c[S_TOK - 1];
        const int tbase = mel + (blockIdx.x - NSB) * 8;
        if (tbase >= max_len) return;
        const float4 z = make_float4(0.f, 0.f, 0.f, 0.f);
        const int t0 = tbase + half * 4;
#pragma unroll
        for (int k = 0; k < 4; ++k) {
            const int t = t0 + k;
            if (t < max_len)
                ((float4*)(out + ((size_t)b * max_len + t) * (size_t)D))[lt] = z;
        }
        if (tid < 8 && tbase + tid < max_len)
            mask[(size_t)b * max_len + tbase + tid] = 1.0f;
    }
}

extern "C" void kernel_launch(void* const* d_in, const int* in_sizes, int n_in,
                              void* d_out, int out_size, void* d_ws, size_t ws_size,
                              hipStream_t stream) {
    const float* x = (const float*)d_in[0];
    const int* dur = (const int*)d_in[1];
    float* out = (float*)d_out;

    const int D = in_sizes[0] / in_sizes[1];                 // 512
    const int max_len = (out_size / B_SZ - 1) / (D + 1);     // data-dependent, from out_size

    int* csum = (int*)d_ws;                                  // B*S ints = 128 KB
    float* mel_len = out + (size_t)B_SZ * max_len * D;
    float* mask = mel_len + B_SZ;

    lr_scan_kernel<<<B_SZ, 64, 0, stream>>>(dur, csum, mel_len);

    // tail worst case: mel >= S_TOK (dur >= 1); 8 frames per tail block.
    const int tail_blocks = (max_len > S_TOK) ? ((max_len - S_TOK + 7) / 8 + 1) : 1;
    dim3 fgrid((unsigned)(NSB + tail_blocks), (unsigned)B_SZ);
    lr_fused_kernel<<<fgrid, 256, 0, stream>>>(x, csum, out, mask, D, max_len);
}